// Round 1
// 328.043 us; speedup vs baseline: 1.0265x; 1.0265x over previous
//
#include <hip/hip_runtime.h>

typedef unsigned int uint32;
typedef unsigned short u16;
typedef __attribute__((ext_vector_type(8))) short short8;
typedef __attribute__((ext_vector_type(4))) float f32x4;

#define NG 1024

__device__ __forceinline__ u16 f2bf(float f) {
  uint32 u = __builtin_bit_cast(uint32, f);
  u += 0x7fffu + ((u >> 16) & 1u);   // round-to-nearest-even
  return (u16)(u >> 16);
}

// async global->LDS DMA, 16B per lane; LDS dest must be wave-uniform base (HW adds lane*16)
__device__ __forceinline__ void glds16(const void* g, void* l) {
  __builtin_amdgcn_global_load_lds((const __attribute__((address_space(1))) void*)g,
                                   (__attribute__((address_space(3))) void*)l,
                                   16, 0, 0);
}

// ---- transpose-only now: M=bf16(A^T), MT=bf16(A), P=bf16(I+A^T). 256 blocks. ----
__global__ __launch_bounds__(256) void k_pre(const float* __restrict__ A,
                                             u16* __restrict__ M,
                                             u16* __restrict__ MT,
                                             u16* __restrict__ P) {
  __shared__ float tile[64][65];
  const int t = threadIdx.x;
  const int bi = blockIdx.x & 15;
  const int bj = blockIdx.x >> 4;
  const int i0 = bi * 64, j0 = bj * 64;
  const int rl = t >> 2;
  const int q = t & 3;
#pragma unroll
  for (int s = 0; s < 4; ++s) {
    int c4 = (q + s * 4) * 4;
    float4 v = *(const float4*)&A[(size_t)(j0 + rl) * NG + i0 + c4];
    tile[rl][c4 + 0] = v.x;
    tile[rl][c4 + 1] = v.y;
    tile[rl][c4 + 2] = v.z;
    tile[rl][c4 + 3] = v.w;
    u16 h0 = f2bf(v.x), h1 = f2bf(v.y), h2 = f2bf(v.z), h3 = f2bf(v.w);
    uint2 pk;
    pk.x = (uint32)h0 | ((uint32)h1 << 16);
    pk.y = (uint32)h2 | ((uint32)h3 << 16);
    *(uint2*)&MT[(size_t)(j0 + rl) * NG + i0 + c4] = pk;   // MT = (A^T)^T = A
  }
  __syncthreads();
#pragma unroll
  for (int s = 0; s < 4; ++s) {
    int c4 = (q + s * 4) * 4;
    int gi = i0 + rl;
    u16 mh[4], ph[4];
#pragma unroll
    for (int u = 0; u < 4; ++u) {
      float f = tile[c4 + u][rl];                 // = M[gi][j0+c4+u]
      mh[u] = f2bf(f);
      float pf = f + ((gi == (j0 + c4 + u)) ? 1.0f : 0.0f);
      ph[u] = f2bf(pf);
    }
    uint2 mk, pkk;
    mk.x = (uint32)mh[0] | ((uint32)mh[1] << 16);
    mk.y = (uint32)mh[2] | ((uint32)mh[3] << 16);
    pkk.x = (uint32)ph[0] | ((uint32)ph[1] << 16);
    pkk.y = (uint32)ph[2] | ((uint32)ph[3] << 16);
    *(uint2*)&M[(size_t)gi * NG + j0 + c4] = mk;
    *(uint2*)&P[(size_t)gi * NG + j0 + c4] = pkk;
  }
}

// swizzled LDS tile read: linear [64][128B] tile, chunk-XOR ((r&7)<<4)
__device__ __forceinline__ short8 ldfrag(const u16* tile, int r, int kkB) {
  const char* p = (const char*)tile + r * 128 + (kkB ^ ((r & 7) << 4));
  return __builtin_bit_cast(short8, *(const uint4*)p);
}

// ---------------- C = A@B, bf16; B passed TRANSPOSED (BT[n][k]).
// global_load_lds double-buffered pipeline, counted vmcnt, 2 raw barriers/K-step. ----
__device__ __forceinline__ void mm_body(const u16* __restrict__ A,
                                        const u16* __restrict__ BT,
                                        u16* __restrict__ C,
                                        u16* __restrict__ CT,
                                        u16* __restrict__ CTI,
                                        int bid) {
  __shared__ __align__(16) u16 sA[2][4096];
  __shared__ __align__(16) u16 sB[2][4096];
  const int t = threadIdx.x;
  const int bm = (bid & 15) * 64;
  const int bn = (bid >> 4) * 64;
  const int wv = t >> 6;
  const int lane = t & 63;
  const int quad = lane >> 4;
  const int l15 = lane & 15;
  const int m0w = (wv & 3) * 16;   // 16-row strip per wave
  const int n0w = (wv >> 2) * 32;  // 32-col strip per wave

  // staging: LDS is linear (slot t*16B); global source col is inverse-swizzled
  const int srow = t >> 3;                 // 0..63
  const int scolb = (t & 7) << 4;          // byte col 0..112
  const int scol = (scolb ^ ((srow & 7) << 4)) >> 1;  // elem col
  const u16* aS = A + (size_t)(bm + srow) * NG + scol;
  const u16* bS = BT + (size_t)(bn + srow) * NG + scol;
  u16* ldA0 = &sA[0][wv << 9];
  u16* ldA1 = &sA[1][wv << 9];
  u16* ldB0 = &sB[0][wv << 9];
  u16* ldB1 = &sB[1][wv << 9];

  f32x4 acc[2];
  acc[0] = (f32x4){0.f, 0.f, 0.f, 0.f};
  acc[1] = (f32x4){0.f, 0.f, 0.f, 0.f};

  glds16(aS, ldA0);
  glds16(bS, ldB0);

#pragma unroll 2
  for (int kb = 0; kb < 16; ++kb) {
    const int cur = kb & 1;
    if (kb < 15) {
      glds16(aS + (kb + 1) * 64, cur ? ldA0 : ldA1);
      glds16(bS + (kb + 1) * 64, cur ? ldB0 : ldB1);
      asm volatile("s_waitcnt vmcnt(2)" ::: "memory");  // wait only kb's stage; kb+1 in flight
    } else {
      asm volatile("s_waitcnt vmcnt(0)" ::: "memory");
    }
    __builtin_amdgcn_s_barrier();
    __builtin_amdgcn_sched_barrier(0);
    const u16* At = sA[cur];
    const u16* Bt = sB[cur];
#pragma unroll
    for (int ks = 0; ks < 2; ++ks) {
      int kkB = ks * 64 + quad * 16;
      short8 af = ldfrag(At, m0w + l15, kkB);
      short8 b0 = ldfrag(Bt, n0w + l15, kkB);
      short8 b1 = ldfrag(Bt, n0w + 16 + l15, kkB);
      acc[0] = __builtin_amdgcn_mfma_f32_16x16x32_bf16(af, b0, acc[0], 0, 0, 0);
      acc[1] = __builtin_amdgcn_mfma_f32_16x16x32_bf16(af, b1, acc[1], 0, 0, 0);
    }
    __builtin_amdgcn_sched_barrier(0);
    __builtin_amdgcn_s_barrier();   // protect buffer about to be re-staged
  }

#pragma unroll
  for (int cb = 0; cb < 2; ++cb) {
    int gcol = bn + n0w + cb * 16 + l15;
    int grow = bm + m0w + quad * 4;
    f32x4 v = acc[cb];
    u16 h[4], hI[4];
#pragma unroll
    for (int rr = 0; rr < 4; ++rr) {
      float f = v[rr];
      h[rr] = f2bf(f);
      hI[rr] = f2bf(f + ((gcol == grow + rr) ? 1.0f : 0.0f));
    }
    if (C) {
#pragma unroll
      for (int rr = 0; rr < 4; ++rr) C[(size_t)(grow + rr) * NG + gcol] = h[rr];
    }
    if (CT) {
      uint2 pk;
      pk.x = (uint32)h[0] | ((uint32)h[1] << 16);
      pk.y = (uint32)h[2] | ((uint32)h[3] << 16);
      *(uint2*)&CT[(size_t)gcol * NG + grow] = pk;
    }
    if (CTI) {
      uint2 pk;
      pk.x = (uint32)hI[0] | ((uint32)hI[1] << 16);
      pk.y = (uint32)hI[2] | ((uint32)hI[3] << 16);
      *(uint2*)&CTI[(size_t)gcol * NG + grow] = pk;
    }
  }
}

__global__ __launch_bounds__(512) void k_mm1(const u16* __restrict__ A,
                                             const u16* __restrict__ BT,
                                             u16* __restrict__ C,
                                             u16* __restrict__ CT,
                                             u16* __restrict__ CTI) {
  mm_body(A, BT, C, CT, CTI, blockIdx.x);
}

__global__ __launch_bounds__(512) void k_mm_dual(const u16* __restrict__ A0,
                                                 const u16* __restrict__ BT0,
                                                 u16* __restrict__ CTI0,
                                                 const u16* __restrict__ A1,
                                                 const u16* __restrict__ BT1,
                                                 u16* __restrict__ C1) {
  if (blockIdx.x < 256)
    mm_body(A0, BT0, nullptr, nullptr, CTI0, blockIdx.x);
  else
    mm_body(A1, BT1, C1, nullptr, nullptr, blockIdx.x - 256);
}

__global__ __launch_bounds__(512) void k_mm3(const u16* __restrict__ A,
                                             const u16* __restrict__ BT,
                                             u16* __restrict__ C) {
  mm_body(A, BT, C, nullptr, nullptr, blockIdx.x);
}

// sigT: dense [64][128] u16 with chunk-XOR swizzle ((d^(d>>3))&7)<<4 on byte-col.
// Scalar transpose writes ~2-way (was ~32-way at pitch 136); b128 reads conflict-free.
__device__ __forceinline__ int sigT_byte(int d, int jb) {
  return (d << 8) + (jb ^ (((d ^ (d >> 3)) & 7) << 4));
}

// ---------------- fused: sigma = mu+eps*exp(ls) (+store), gather W[idx,idx], bmm ----
__global__ __launch_bounds__(256) void k_bmm(const u16* __restrict__ W,
                                             const float* __restrict__ mu,
                                             const float* __restrict__ ls,
                                             const float* __restrict__ ep,
                                             const int* __restrict__ nidx,
                                             float* __restrict__ sig,
                                             float* __restrict__ z) {
  __shared__ __align__(16) u16 s_sub[128][136];
  __shared__ __align__(16) u16 s_sigT[8192];
  __shared__ __align__(16) u16 s_row[4][2][1024];   // per-wave double-buffered row
  __shared__ int s_idx[128];

  const int b = blockIdx.x;
  const int t = threadIdx.x;
  const int w = t >> 6;
  const int lane = t & 63;

  if (t < 128) s_idx[t] = nidx[b * 128 + t];

  {  // sigma fused: read mu/ls/ep once, write sig (streaming), stage bf16 sigT
    const size_t off = (size_t)b * 2048;  // float4 units
    const f32x4* mp = (const f32x4*)mu + off;
    const f32x4* lp = (const f32x4*)ls + off;
    const f32x4* epp = (const f32x4*)ep + off;
    f32x4* sp = (f32x4*)sig + off;
#pragma unroll
    for (int q = 0; q < 8; ++q) {
      int f = t + q * 256;
      f32x4 m = __builtin_nontemporal_load(mp + f);
      f32x4 l = __builtin_nontemporal_load(lp + f);
      f32x4 e = __builtin_nontemporal_load(epp + f);
      f32x4 v;
      v.x = m.x + e.x * expf(l.x);
      v.y = m.y + e.y * expf(l.y);
      v.z = m.z + e.z * expf(l.z);
      v.w = m.w + e.w * expf(l.w);
      __builtin_nontemporal_store(v, sp + f);   // sig never re-read (LDS copy feeds MFMA)
      int j = f >> 4;            // k index 0..127
      int d0 = (f & 15) << 2;    // d index 0..63
      *(u16*)((char*)s_sigT + sigT_byte(d0 + 0, j << 1)) = f2bf(v.x);
      *(u16*)((char*)s_sigT + sigT_byte(d0 + 1, j << 1)) = f2bf(v.y);
      *(u16*)((char*)s_sigT + sigT_byte(d0 + 2, j << 1)) = f2bf(v.z);
      *(u16*)((char*)s_sigT + sigT_byte(d0 + 3, j << 1)) = f2bf(v.w);
    }
  }
  __syncthreads();

  {  // W row broadcast via LDS-DMA (no VGPR round-trip, conflict-free writes), then gather
    const int gc0 = s_idx[2 * lane];
    const int gc1 = s_idx[2 * lane + 1];
    int r0 = s_idx[w];
    glds16(W + (size_t)r0 * NG + lane * 8, &s_row[w][0][0]);
    glds16(W + (size_t)r0 * NG + 512 + lane * 8, &s_row[w][0][512]);
    for (int it = 0; it < 32; ++it) {
      const int cb = it & 1;
      if (it < 31) {
        int rn = s_idx[w + (it + 1) * 4];
        glds16(W + (size_t)rn * NG + lane * 8, &s_row[w][cb ^ 1][0]);
        glds16(W + (size_t)rn * NG + 512 + lane * 8, &s_row[w][cb ^ 1][512]);
        asm volatile("s_waitcnt vmcnt(2)" ::: "memory");  // current row landed; next in flight
      } else {
        asm volatile("s_waitcnt vmcnt(0)" ::: "memory");
      }
      int i = w + it * 4;
      uint32 lo = s_row[w][cb][gc0];
      uint32 hi = s_row[w][cb][gc1];
      *(uint32*)&s_sub[i][2 * lane] = lo | (hi << 16);  // packed b32, 2-way free
    }
  }
  __syncthreads();

  const int quad = lane >> 4;
  const int l15 = lane & 15;
  f32x4 acc[2][4];
#pragma unroll
  for (int a = 0; a < 2; ++a)
#pragma unroll
    for (int c = 0; c < 4; ++c) acc[a][c] = (f32x4){0.f, 0.f, 0.f, 0.f};

#pragma unroll
  for (int kt = 0; kt < 4; ++kt) {
    int kk = kt * 32 + quad * 8;
    short8 a0 = __builtin_bit_cast(short8, *(const uint4*)&s_sub[w * 32 + l15][kk]);
    short8 a1 = __builtin_bit_cast(short8, *(const uint4*)&s_sub[w * 32 + 16 + l15][kk]);
#pragma unroll
    for (int ct = 0; ct < 4; ++ct) {
      short8 bf = __builtin_bit_cast(
          short8, *(const uint4*)((const char*)s_sigT + sigT_byte(ct * 16 + l15, kk << 1)));
      acc[0][ct] = __builtin_amdgcn_mfma_f32_16x16x32_bf16(a0, bf, acc[0][ct], 0, 0, 0);
      acc[1][ct] = __builtin_amdgcn_mfma_f32_16x16x32_bf16(a1, bf, acc[1][ct], 0, 0, 0);
    }
  }

#pragma unroll
  for (int rt = 0; rt < 2; ++rt) {
    int gr0 = b * 128 + w * 32 + rt * 16 + quad * 4;
#pragma unroll
    for (int ct = 0; ct < 4; ++ct) {
      int col = ct * 16 + l15;
#pragma unroll
      for (int r = 0; r < 4; ++r) {
        z[(size_t)(gr0 + r) * 64 + col] = acc[rt][ct][r];
      }
    }
  }
}

extern "C" void kernel_launch(void* const* d_in, const int* in_sizes, int n_in,
                              void* d_out, int out_size, void* d_ws, size_t ws_size,
                              hipStream_t stream) {
  const float* A  = (const float*)d_in[0];
  const float* mu = (const float*)d_in[1];
  const float* ls = (const float*)d_in[2];
  const float* ep = (const float*)d_in[3];
  const int* nidx = (const int*)d_in[4];

  float* sig = (float*)d_out;                 // 16777216 floats
  float* z   = sig + (size_t)16777216;        // 16777216 floats

  u16* base = (u16*)d_ws;                     // 16 MB of ws
  const size_t MM = (size_t)NG * NG;
  u16* M      = base + 0 * MM;
  u16* MT     = base + 1 * MM;
  u16* P      = base + 2 * MM;
  u16* Msq    = base + 3 * MM;
  u16* MsqT   = base + 4 * MM;
  u16* MsqTI  = base + 5 * MM;
  u16* M4TI   = base + 6 * MM;
  u16* B2     = base + 7 * MM;
  u16* W      = Msq;                          // reuse: Msq dead after dual

  k_pre<<<256, 256, 0, stream>>>(A, M, MT, P);
  // W = (I - A^T)^{-1} ~= (I+M)(I+M^2)(I+M^4), M = A^T  (err ~0.32^8 ~ 1e-4)
  k_mm1<<<256, 512, 0, stream>>>(M, MT, Msq, MsqT, MsqTI);          // M^2, M^2T, I+M^2T
  k_mm_dual<<<512, 512, 0, stream>>>(Msq, MsqT, M4TI,               // (I+M^4)^T
                                     P, MsqTI, B2);                 // B2=(I+M)(I+M^2)
  k_mm3<<<256, 512, 0, stream>>>(B2, M4TI, W);                      // W = B2(I+M^4)
  k_bmm<<<2048, 256, 0, stream>>>(W, mu, ls, ep, nidx, sig, z);
}